// Round 10
// baseline (176.432 us; speedup 1.0000x reference)
//
#include <hip/hip_runtime.h>
#include <hip/hip_bf16.h>
#include <stdint.h>

// PSM cosine cost volume, MI355X (gfx950).
// out[b,d,h,w] = (1/C) * sum_c L[b,c,h,w] * R[b,c,h,w-d],  0 where w<d.
// Banded Gram matrix via bf16 MFMA 16x16x32.
//
// R10: occupancy/TLP push. KC=32 (16 chunks), single-buffer LDS 16.6KB,
// prefetch regs halved (~32), amdgpu_waves_per_eu(6) caps VGPR at 85 ->
// 6 blocks/CU resident = the ENTIRE 1536-block grid in one generation
// (1536 = 6*256), 24 waves/CU of latency hiding, finer demand bursts.
// Measured R5-R9: __launch_bounds__ 2nd arg budgets VGPR as waves/EU=2*arg
// ((.,4)->cap 64 + spill; (.,2)->cap 128); use waves_per_eu for upward control.
//
// LDS row = 80 bytes: 4 used 16B slots + 16B pad (pad breaks the 64B=half-bank
// periodicity; writes ~4-way, reads ~2-way). Slot s holds c in [8s',8s'+8),
// s = (s' ^ (lw&3) ^ ((lw>>2)&3) ^ ((lw>>4)&3)) & 3; the (lw>>2),(lw>>4) terms
// are wave-uniform at read (tile index) per 16-row fragment -> reads stay
// single ds_read_b128. Dword in slot = c-pair (rp&3); bf16 pair=(even,odd c).

#define B_ 4
#define C_ 512
#define H_ 96
#define W_ 312
#define D_ 48
#define HW_ (H_ * W_)      // 29952
#define CHW_ (C_ * HW_)

#define KC 32              // staged c per chunk
#define NCHUNK (C_ / KC)   // 16
#define NQ 4               // quarters per row
#define QW 80              // quarter width (last covers w=240..311, guarded)
#define LCOLS 80           // 5 N-tiles of 16
#define RCOLS 128          // [wq-48, wq+80): 8 M-tiles of 16
#define PITCH 80           // LDS row pitch BYTES (4x16B slots + 16B pad)
#define LBYTES (LCOLS * PITCH)          // 6400
#define RBYTES (RCOLS * PITCH)          // 10240
#define SMEM_BYTES (LBYTES + RBYTES)    // 16640 >= out staging 15360

#define THREADS 256
#define NWG (NQ * H_ * B_)  // 1536 blocks = 6 per CU, one generation
#define LITEMS 2            // 16 c-pairs x 20 q = 320 items; it=1: tid<64 (wave0)
#define RITEMS 2            // 16 x 32 = 512 items exactly

typedef __bf16 bf16x8 __attribute__((ext_vector_type(8)));
typedef float  f32x4  __attribute__((ext_vector_type(4)));

// RNE pack of two f32 -> packed 2xbf16 (a = low half = even c), 1 VALU op.
__device__ __forceinline__ uint32_t pack2_bf16(float a, float b) {
    uint32_t r;
    asm("v_cvt_pk_bf16_f32 %0, %1, %2" : "=v"(r) : "v"(a), "v"(b));
    return r;
}

// Byte offset of the 16B slot holding c-range [8*chi, 8*chi+8) of row lw.
__device__ __forceinline__ int lds_slotoff(int lw, int chi) {
    int s = (chi ^ (lw & 3) ^ ((lw >> 2) & 3) ^ ((lw >> 4) & 3)) & 3;
    return lw * PITCH + (s << 4);
}

// LDS-only drain + barrier (keeps global loads in flight across the barrier).
__device__ __forceinline__ void lds_barrier() {
    asm volatile("s_waitcnt lgkmcnt(0)" ::: "memory");
    __builtin_amdgcn_s_barrier();
}

__global__ __launch_bounds__(THREADS)
__attribute__((amdgpu_waves_per_eu(6)))   // VGPR cap 512/6=85 -> 6 blocks/CU
void psm_cost_volume(const float* __restrict__ lf,
                     const float* __restrict__ rf,
                     float* __restrict__ out) {
    // Bijective XCD swizzle: xcd = lid%8 owns 192 consecutive logical ids.
    const int lid = blockIdx.x;
    const int swz = (lid & 7) * (NWG / 8) + (lid >> 3);
    const int q   = swz & 3;
    const int t   = swz >> 2;          // 0..383
    const int b   = t / H_;
    const int h   = t - b * H_;
    const int wq  = q * QW;            // 0,80,160,240

    const int tid  = threadIdx.x;
    const int lane = tid & 63;
    const int wave = tid >> 6;          // 4 waves
    const int l15  = lane & 15;
    const int l4   = lane >> 4;
    const int jj   = wave;              // A-tile offset 0..3

    extern __shared__ char smem[];
    // [0, LBYTES): L rows lw=0..79   (w  = wq + lw)
    // [LBYTES, +RBYTES): R rows lw=0..127 (w' = wq - 48 + lw)
    // epilogue reuses [0, 15360) as f32 out staging

    const float* lbase = lf + (size_t)b * CHW_ + (size_t)h * W_;
    const float* rbase = rf + (size_t)b * CHW_ + (size_t)h * W_;

    f32x4 acc[5];
    #pragma unroll
    for (int i = 0; i < 5; ++i) acc[i] = f32x4{0.f, 0.f, 0.f, 0.f};

    // prefetch registers, one chunk deep: 4 items x 2 planes = 32 VGPR
    f32x4 pl0[LITEMS], pl1[LITEMS], pr0[RITEMS], pr1[RITEMS];

    // ---- issue loads for chunk starting at channel c0 into prefetch regs ----
    auto LOADS = [&](int c0) {
        #pragma unroll
        for (int it = 0; it < LITEMS; ++it) {
            int idx = tid + it * THREADS;        // coalesced runs in w
            if (idx < 16 * 20) {                 // it=1: tid<64 (wave0, uniform)
                int rp = idx / 20;               // c-pair 0..15
                int q4 = idx - rp * 20;          // float4 column 0..19
                int w4 = wq + 4 * q4;
                pl0[it] = f32x4{0.f, 0.f, 0.f, 0.f};
                pl1[it] = f32x4{0.f, 0.f, 0.f, 0.f};
                if (w4 + 3 < W_) {               // quarter3 tail OOB -> zeros
                    const float* g = lbase + (size_t)(c0 + 2 * rp) * HW_ + w4;
                    pl0[it] = *(const f32x4*)g;
                    pl1[it] = *(const f32x4*)(g + HW_);
                }
            }
        }
        #pragma unroll
        for (int it = 0; it < RITEMS; ++it) {
            int idx = tid + it * THREADS;
            int rp  = idx >> 5;                  // c-pair 0..15
            int q4  = idx & 31;                  // float4 column 0..31
            int w4  = wq - 48 + 4 * q4;          // may be <0 or >=W -> zeros
            pr0[it] = f32x4{0.f, 0.f, 0.f, 0.f};
            pr1[it] = f32x4{0.f, 0.f, 0.f, 0.f};
            if (w4 >= 0 && w4 + 3 < W_) {
                const float* g = rbase + (size_t)(c0 + 2 * rp) * HW_ + w4;
                pr0[it] = *(const f32x4*)g;
                pr1[it] = *(const f32x4*)(g + HW_);
            }
        }
    };

    // ---- pack prefetch regs -> LDS (vmcnt-waits exactly the loads used) ----
    auto WRITES = [&]() {
        #pragma unroll
        for (int it = 0; it < LITEMS; ++it) {
            int idx = tid + it * THREADS;
            if (idx < 16 * 20) {
                int rp  = idx / 20;
                int q4  = idx - rp * 20;
                int chi = rp >> 2;
                int cb  = (rp & 3) << 2;
                #pragma unroll
                for (int j = 0; j < 4; ++j) {
                    int lw = 4 * q4 + j;
                    *(uint32_t*)(smem + lds_slotoff(lw, chi) + cb) =
                        pack2_bf16(pl0[it][j], pl1[it][j]);
                }
            }
        }
        #pragma unroll
        for (int it = 0; it < RITEMS; ++it) {
            int idx = tid + it * THREADS;
            int rp  = idx >> 5;
            int q4  = idx & 31;
            int chi = rp >> 2;
            int cb  = (rp & 3) << 2;
            #pragma unroll
            for (int j = 0; j < 4; ++j) {
                int lw = 4 * q4 + j;
                *(uint32_t*)(smem + LBYTES + lds_slotoff(lw, chi) + cb) =
                    pack2_bf16(pr0[it][j], pr1[it][j]);
            }
        }
    };

    LOADS(0);
    for (int ch = 0; ch < NCHUNK; ++ch) {
        if (ch) lds_barrier();          // all waves done reading chunk ch-1
        WRITES();                       // stage chunk ch (vmcnt-waits its loads)
        if (ch + 1 < NCHUNK) LOADS((ch + 1) * KC);  // in flight across compute
        lds_barrier();                  // ds_writes visible; vmcnt NOT drained

        // ---- compute: 5 n-tiles, wave = jj; 1 MFMA each (K=KC=32) ----
        #pragma unroll
        for (int pi = 0; pi < 5; ++pi) {
            const int lwB = 16 * pi + l15;              // L row
            const int lwA = 16 * (pi + jj) + l15;       // R row
            bf16x8 bfrag = *(const bf16x8*)(smem + lds_slotoff(lwB, l4));
            bf16x8 afrag = *(const bf16x8*)(smem + LBYTES + lds_slotoff(lwA, l4));
            acc[pi] = __builtin_amdgcn_mfma_f32_16x16x32_bf16(afrag, bfrag, acc[pi], 0, 0, 0);
        }
    }
    __syncthreads();   // epilogue overwrites LDS; nothing left in flight

    // ---- scatter accumulators -> LDS [D_][QW] f32 ----
    // D[m][n]: col tn = l15, row tm = 4*l4 + r.
    // w = wq + 16n + tn ; w' = wq - 48 + 16(n+jj) + tm ; d = 48 - 16*jj + tn - tm
    float* outs = (float*)smem;
    #pragma unroll
    for (int pi = 0; pi < 5; ++pi) {
        const int lw = 16 * pi + l15;   // 0..79
        #pragma unroll
        for (int r = 0; r < 4; ++r) {
            int tm = 4 * l4 + r;
            int d  = 48 - 16 * jj + l15 - tm;
            if (d >= 0 && d < D_) {
                outs[d * QW + lw] = acc[pi][r] * (1.f / 512.f);
            }
        }
    }
    __syncthreads();

    // ---- coalesced global store (guard w < W_ for last quarter) ----
    float* obase = out + (size_t)b * (D_ * HW_) + (size_t)h * W_ + wq;
    #pragma unroll
    for (int it = 0; it < (D_ * QW) / THREADS; ++it) {   // 15 iters
        int idx = it * THREADS + tid;
        int d   = idx / QW;
        int lw  = idx - d * QW;
        if (wq + lw < W_) {
            obase[(size_t)d * HW_ + lw] = outs[idx];
        }
    }
}

extern "C" void kernel_launch(void* const* d_in, const int* in_sizes, int n_in,
                              void* d_out, int out_size, void* d_ws, size_t ws_size,
                              hipStream_t stream) {
    const float* lf = (const float*)d_in[0];
    const float* rf = (const float*)d_in[1];
    float* out = (float*)d_out;
    psm_cost_volume<<<dim3(NWG), THREADS, SMEM_BYTES, stream>>>(lf, rf, out);
}

// Round 11
// 112.301 us; speedup vs baseline: 1.5711x; 1.5711x over previous
//
#include <hip/hip_runtime.h>
#include <hip/hip_bf16.h>
#include <stdint.h>

// PSM cosine cost volume, MI355X (gfx950).
// out[b,d,h,w] = (1/C) * sum_c L[b,c,h,w] * R[b,c,h,w-d],  0 where w<d.
// Banded Gram matrix via bf16 MFMA 16x16x32.
//
// R11 = R10 geometry (KC=32, single-buffer LDS 16.6KB, 256 threads, PITCH=80,
// XCD swizzle) with the occupancy mechanism swapped:
//   __launch_bounds__(256, 3)  ->  VGPR cap 512/(2*3) = 85 (measured model:
//   R5/R7 arg4->64, R6 arg2->128). Kernel needs ~72 -> NO SPILL, 6 blocks/CU
//   = 24 waves/CU. R10's amdgpu_waves_per_eu(6) made the compiler shrink to
//   40 VGPR and spill the prefetch (+190MB scratch traffic, 176us).
//
// LDS row = 80 bytes: 4 used 16B slots + 16B pad. Slot s holds c-range
// [8s',8s'+8), s = (s' ^ (lw&3) ^ ((lw>>2)&3) ^ ((lw>>4)&3)) & 3; the
// (lw>>2),(lw>>4) terms are wave-uniform at read per 16-row fragment ->
// reads stay single ds_read_b128. Dword in slot = c-pair (rp&3);
// bf16 pair = (even c, odd c).

#define B_ 4
#define C_ 512
#define H_ 96
#define W_ 312
#define D_ 48
#define HW_ (H_ * W_)      // 29952
#define CHW_ (C_ * HW_)

#define KC 32              // staged c per chunk
#define NCHUNK (C_ / KC)   // 16
#define NQ 4               // quarters per row
#define QW 80              // quarter width (last covers w=240..311, guarded)
#define LCOLS 80           // 5 N-tiles of 16
#define RCOLS 128          // [wq-48, wq+80): 8 M-tiles of 16
#define PITCH 80           // LDS row pitch BYTES (4x16B slots + 16B pad)
#define LBYTES (LCOLS * PITCH)          // 6400
#define RBYTES (RCOLS * PITCH)          // 10240
#define SMEM_BYTES (LBYTES + RBYTES)    // 16640 >= out staging 15360

#define THREADS 256
#define NWG (NQ * H_ * B_)  // 1536 blocks
#define LITEMS 2            // 16 c-pairs x 20 q = 320 items; it=1: tid<64 (wave0)
#define RITEMS 2            // 16 x 32 = 512 items exactly

typedef __bf16 bf16x8 __attribute__((ext_vector_type(8)));
typedef float  f32x4  __attribute__((ext_vector_type(4)));

// RNE pack of two f32 -> packed 2xbf16 (a = low half = even c), 1 VALU op.
__device__ __forceinline__ uint32_t pack2_bf16(float a, float b) {
    uint32_t r;
    asm("v_cvt_pk_bf16_f32 %0, %1, %2" : "=v"(r) : "v"(a), "v"(b));
    return r;
}

// Byte offset of the 16B slot holding c-range [8*chi, 8*chi+8) of row lw.
__device__ __forceinline__ int lds_slotoff(int lw, int chi) {
    int s = (chi ^ (lw & 3) ^ ((lw >> 2) & 3) ^ ((lw >> 4) & 3)) & 3;
    return lw * PITCH + (s << 4);
}

// LDS-only drain + barrier (keeps global loads in flight across the barrier).
__device__ __forceinline__ void lds_barrier() {
    asm volatile("s_waitcnt lgkmcnt(0)" ::: "memory");
    __builtin_amdgcn_s_barrier();
}

__global__ __launch_bounds__(THREADS, 3)   // VGPR cap ~85 -> 24 waves/CU, no spill
void psm_cost_volume(const float* __restrict__ lf,
                     const float* __restrict__ rf,
                     float* __restrict__ out) {
    // Bijective XCD swizzle: xcd = lid%8 owns 192 consecutive logical ids.
    const int lid = blockIdx.x;
    const int swz = (lid & 7) * (NWG / 8) + (lid >> 3);
    const int q   = swz & 3;
    const int t   = swz >> 2;          // 0..383
    const int b   = t / H_;
    const int h   = t - b * H_;
    const int wq  = q * QW;            // 0,80,160,240

    const int tid  = threadIdx.x;
    const int lane = tid & 63;
    const int wave = tid >> 6;          // 4 waves
    const int l15  = lane & 15;
    const int l4   = lane >> 4;
    const int jj   = wave;              // A-tile offset 0..3

    extern __shared__ char smem[];
    // [0, LBYTES): L rows lw=0..79   (w  = wq + lw)
    // [LBYTES, +RBYTES): R rows lw=0..127 (w' = wq - 48 + lw)
    // epilogue reuses [0, 15360) as f32 out staging

    const float* lbase = lf + (size_t)b * CHW_ + (size_t)h * W_;
    const float* rbase = rf + (size_t)b * CHW_ + (size_t)h * W_;

    f32x4 acc[5];
    #pragma unroll
    for (int i = 0; i < 5; ++i) acc[i] = f32x4{0.f, 0.f, 0.f, 0.f};

    // prefetch registers, one chunk deep: 4 items x 2 planes = 32 VGPR
    f32x4 pl0[LITEMS], pl1[LITEMS], pr0[RITEMS], pr1[RITEMS];

    // ---- issue loads for chunk starting at channel c0 into prefetch regs ----
    auto LOADS = [&](int c0) {
        #pragma unroll
        for (int it = 0; it < LITEMS; ++it) {
            int idx = tid + it * THREADS;        // coalesced runs in w
            if (idx < 16 * 20) {                 // it=1: tid<64 (wave0, uniform)
                int rp = idx / 20;               // c-pair 0..15
                int q4 = idx - rp * 20;          // float4 column 0..19
                int w4 = wq + 4 * q4;
                pl0[it] = f32x4{0.f, 0.f, 0.f, 0.f};
                pl1[it] = f32x4{0.f, 0.f, 0.f, 0.f};
                if (w4 + 3 < W_) {               // quarter3 tail OOB -> zeros
                    const float* g = lbase + (size_t)(c0 + 2 * rp) * HW_ + w4;
                    pl0[it] = *(const f32x4*)g;
                    pl1[it] = *(const f32x4*)(g + HW_);
                }
            }
        }
        #pragma unroll
        for (int it = 0; it < RITEMS; ++it) {
            int idx = tid + it * THREADS;
            int rp  = idx >> 5;                  // c-pair 0..15
            int q4  = idx & 31;                  // float4 column 0..31
            int w4  = wq - 48 + 4 * q4;          // may be <0 or >=W -> zeros
            pr0[it] = f32x4{0.f, 0.f, 0.f, 0.f};
            pr1[it] = f32x4{0.f, 0.f, 0.f, 0.f};
            if (w4 >= 0 && w4 + 3 < W_) {
                const float* g = rbase + (size_t)(c0 + 2 * rp) * HW_ + w4;
                pr0[it] = *(const f32x4*)g;
                pr1[it] = *(const f32x4*)(g + HW_);
            }
        }
    };

    // ---- pack prefetch regs -> LDS (vmcnt-waits exactly the loads used) ----
    auto WRITES = [&]() {
        #pragma unroll
        for (int it = 0; it < LITEMS; ++it) {
            int idx = tid + it * THREADS;
            if (idx < 16 * 20) {
                int rp  = idx / 20;
                int q4  = idx - rp * 20;
                int chi = rp >> 2;
                int cb  = (rp & 3) << 2;
                #pragma unroll
                for (int j = 0; j < 4; ++j) {
                    int lw = 4 * q4 + j;
                    *(uint32_t*)(smem + lds_slotoff(lw, chi) + cb) =
                        pack2_bf16(pl0[it][j], pl1[it][j]);
                }
            }
        }
        #pragma unroll
        for (int it = 0; it < RITEMS; ++it) {
            int idx = tid + it * THREADS;
            int rp  = idx >> 5;
            int q4  = idx & 31;
            int chi = rp >> 2;
            int cb  = (rp & 3) << 2;
            #pragma unroll
            for (int j = 0; j < 4; ++j) {
                int lw = 4 * q4 + j;
                *(uint32_t*)(smem + LBYTES + lds_slotoff(lw, chi) + cb) =
                    pack2_bf16(pr0[it][j], pr1[it][j]);
            }
        }
    };

    LOADS(0);
    for (int ch = 0; ch < NCHUNK; ++ch) {
        if (ch) lds_barrier();          // all waves done reading chunk ch-1
        WRITES();                       // stage chunk ch (vmcnt-waits its loads)
        if (ch + 1 < NCHUNK) LOADS((ch + 1) * KC);  // in flight across compute
        lds_barrier();                  // ds_writes visible; vmcnt NOT drained

        // ---- compute: 5 n-tiles, wave = jj; 1 MFMA each (K=KC=32) ----
        #pragma unroll
        for (int pi = 0; pi < 5; ++pi) {
            const int lwB = 16 * pi + l15;              // L row
            const int lwA = 16 * (pi + jj) + l15;       // R row
            bf16x8 bfrag = *(const bf16x8*)(smem + lds_slotoff(lwB, l4));
            bf16x8 afrag = *(const bf16x8*)(smem + LBYTES + lds_slotoff(lwA, l4));
            acc[pi] = __builtin_amdgcn_mfma_f32_16x16x32_bf16(afrag, bfrag, acc[pi], 0, 0, 0);
        }
    }
    __syncthreads();   // epilogue overwrites LDS; nothing left in flight

    // ---- scatter accumulators -> LDS [D_][QW] f32 ----
    // D[m][n]: col tn = l15, row tm = 4*l4 + r.
    // w = wq + 16n + tn ; w' = wq - 48 + 16(n+jj) + tm ; d = 48 - 16*jj + tn - tm
    float* outs = (float*)smem;
    #pragma unroll
    for (int pi = 0; pi < 5; ++pi) {
        const int lw = 16 * pi + l15;   // 0..79
        #pragma unroll
        for (int r = 0; r < 4; ++r) {
            int tm = 4 * l4 + r;
            int d  = 48 - 16 * jj + l15 - tm;
            if (d >= 0 && d < D_) {
                outs[d * QW + lw] = acc[pi][r] * (1.f / 512.f);
            }
        }
    }
    __syncthreads();

    // ---- coalesced global store (guard w < W_ for last quarter) ----
    float* obase = out + (size_t)b * (D_ * HW_) + (size_t)h * W_ + wq;
    #pragma unroll
    for (int it = 0; it < (D_ * QW) / THREADS; ++it) {   // 15 iters
        int idx = it * THREADS + tid;
        int d   = idx / QW;
        int lw  = idx - d * QW;
        if (wq + lw < W_) {
            obase[(size_t)d * HW_ + lw] = outs[idx];
        }
    }
}

extern "C" void kernel_launch(void* const* d_in, const int* in_sizes, int n_in,
                              void* d_out, int out_size, void* d_ws, size_t ws_size,
                              hipStream_t stream) {
    const float* lf = (const float*)d_in[0];
    const float* rf = (const float*)d_in[1];
    float* out = (float*)d_out;
    psm_cost_volume<<<dim3(NWG), THREADS, SMEM_BYTES, stream>>>(lf, rf, out);
}